// Round 1
// baseline (27207.965 us; speedup 1.0000x reference)
//
#include <hip/hip_runtime.h>
#include <math.h>

#define HD 64
#define DATT 16
#define NCIN 3
#define NCOUT 2
#define HH 24
#define WW 48
#define SS (HH*WW)          // 1152
#define NB 16
#define TSTEPS 37
#define INPUT_FRAMES 12

// ---------------- workspace layout (floats) ----------------
#define OFF_H     0            // 16*64*1152 = 1179648
#define OFF_C     1179648
#define OFF_M     2359296
#define OFF_FEED  3538944      // 16*3*1152 = 55296
#define OFF_COMB  3594240      // 16*256*1152 = 4718592
#define OFF_QKV   8312832      // 16*1152*48 = 884736
#define OFF_MKV   9197568      // 16*1152*32 = 589824
#define OFF_Z     9787392      // 16*16*1152 = 294912
#define OFF_IOG   10082304     // 16*192*1152 = 3538944
// total 13621248 floats = ~52 MB

__device__ __forceinline__ float sigmoidf_(float x) {
    return 1.0f / (1.0f + __expf(-x));
}

// ---------------- zero init h, c, m ----------------
__global__ void k_zero(float* __restrict__ p, int n4) {
    int i = blockIdx.x * blockDim.x + threadIdx.x;
    if (i < n4) ((float4*)p)[i] = make_float4(0.f, 0.f, 0.f, 0.f);
}

// ---------------- feed selection ----------------
// x: (N,T,H,W,CIN) ; outbuf: (N,T,COUT,H,W) ; feed: (N,3,H,W)
__global__ void k_feed(const float* __restrict__ x, const float* __restrict__ outbuf,
                       float* __restrict__ feed, int t) {
    int i = blockIdx.x * blockDim.x + threadIdx.x;
    if (i >= NB * 3 * SS) return;
    int s = i % SS;
    int ch = (i / SS) % 3;
    int n = i / (3 * SS);
    int y = s / WW, xx = s % WW;
    float v;
    if (t < INPUT_FRAMES || ch == 2) {
        v = x[(((n * TSTEPS + t) * HH + y) * WW + xx) * NCIN + ch];
    } else {
        v = outbuf[(((n * TSTEPS + (t - 1)) * NCOUT + ch) * HH + y) * WW + xx];
    }
    feed[i] = v;
}

// ---------------- generic 3x3 conv, pad=1, fp32 ----------------
// input = concat([in1 (C1 ch), in2 (C2 ch)]) in NCHW; weights w[oc][c][ky][kx]
// grid: (16n * 3 row-tiles, OC/8); block 192 = 24 col-groups (2 px) x 8 rows
__global__ __launch_bounds__(192) void k_conv3x3(
    const float* __restrict__ in1, int C1,
    const float* __restrict__ in2, int C2,
    const float* __restrict__ w, const float* __restrict__ b,
    float* __restrict__ out, int OC)
{
    __shared__ float lds_patch[8 * 500];   // 8 ch x 10 rows x 50 cols
    __shared__ float lds_w[80 * 72];       // [c][kt][ocl]  (up to 80 in-ch)

    const int bx = blockIdx.x;
    const int n = bx / 3, tile = bx % 3;
    const int ocg = blockIdx.y;
    const int C = C1 + C2;
    const int nchunk = (C + 7) / 8;
    const int tid = threadIdx.x;

    // stage all weights for this oc-group once (zero-padded past C)
    const int wtot = nchunk * 8 * 72;
    for (int i = tid; i < wtot; i += 192) {
        int ocl = i % 8;
        int kt  = (i / 8) % 9;
        int c   = i / 72;
        float val = 0.f;
        if (c < C) val = w[((ocg * 8 + ocl) * C + c) * 9 + kt];
        lds_w[i] = val;
    }

    const int cg = tid % 24;
    const int ty = tid / 24;
    const int x0 = cg * 2;
    const int y_out = tile * 8 + ty;

    float acc[16];
#pragma unroll
    for (int j = 0; j < 16; ++j) acc[j] = 0.f;

    for (int chunk = 0; chunk < nchunk; ++chunk) {
        __syncthreads();
        // stage 8-channel input patch (halo zero-filled)
        for (int i = tid; i < 8 * 500; i += 192) {
            int c_l = i / 500;
            int rem = i % 500;
            int py = rem / 50, px = rem % 50;
            int gy = tile * 8 + py - 1;
            int gx = px - 1;
            int c = chunk * 8 + c_l;
            float val = 0.f;
            if (gy >= 0 && gy < HH && gx >= 0 && gx < WW && c < C) {
                val = (c < C1) ? in1[((n * C1 + c) * HH + gy) * WW + gx]
                               : in2[((n * C2 + (c - C1)) * HH + gy) * WW + gx];
            }
            lds_patch[i] = val;
        }
        __syncthreads();

        for (int icl = 0; icl < 8; ++icl) {
            const int c = chunk * 8 + icl;
            const float* wb_ = &lds_w[c * 72];
            const float* pr = &lds_patch[icl * 500 + ty * 50 + x0];
#pragma unroll
            for (int ky = 0; ky < 3; ++ky) {
                const float* r = pr + ky * 50;
                float i0 = r[0], i1 = r[1], i2 = r[2], i3 = r[3];
                const float* wk = wb_ + ky * 24;
#pragma unroll
                for (int kx = 0; kx < 3; ++kx) {
                    float va = (kx == 0) ? i0 : ((kx == 1) ? i1 : i2);
                    float vb = (kx == 0) ? i1 : ((kx == 1) ? i2 : i3);
                    const float4 wa  = *(const float4*)(wk + kx * 8);
                    const float4 wb4 = *(const float4*)(wk + kx * 8 + 4);
                    acc[0]  += va * wa.x;  acc[1]  += va * wa.y;
                    acc[2]  += va * wa.z;  acc[3]  += va * wa.w;
                    acc[4]  += va * wb4.x; acc[5]  += va * wb4.y;
                    acc[6]  += va * wb4.z; acc[7]  += va * wb4.w;
                    acc[8]  += vb * wa.x;  acc[9]  += vb * wa.y;
                    acc[10] += vb * wa.z;  acc[11] += vb * wa.w;
                    acc[12] += vb * wb4.x; acc[13] += vb * wb4.y;
                    acc[14] += vb * wb4.z; acc[15] += vb * wb4.w;
                }
            }
        }
    }

#pragma unroll
    for (int j = 0; j < 8; ++j) {
        int oc = ocg * 8 + j;
        float bv = b[oc];
        float2 o2 = make_float2(acc[j] + bv, acc[8 + j] + bv);
        *(float2*)&out[((n * OC + oc) * HH + y_out) * WW + x0] = o2;
    }
}

// ---------------- ConvLSTM gates ----------------
__global__ void k_lstm_gates(const float* __restrict__ comb, float* __restrict__ c,
                             float* __restrict__ h) {
    int i = blockIdx.x * blockDim.x + threadIdx.x;
    if (i >= NB * HD * SS) return;
    int s = i % SS;
    int ch = (i / SS) % HD;
    int n = i / (HD * SS);
    const float* cb = comb + (size_t)n * 4 * HD * SS;
    float ci = cb[(ch) * SS + s];
    float cf = cb[(ch + HD) * SS + s];
    float co = cb[(ch + 2 * HD) * SS + s];
    float cg = cb[(ch + 3 * HD) * SS + s];
    float ig = sigmoidf_(ci);
    float fg = sigmoidf_(cf);
    float og = sigmoidf_(co);
    float gg = tanhf(cg);
    float cn = fg * c[i] + ig * gg;
    c[i] = cn;
    h[i] = og * tanhf(cn);
}

// ---------------- 1x1 q/k/v + mk/mv projections ----------------
// outputs: qkv (n,s,48) = [q|k|v], mkv (n,s,32) = [mk|mv]
__global__ void k_qkv(const float* __restrict__ h, const float* __restrict__ m,
                      const float* __restrict__ hw, const float* __restrict__ hb,
                      const float* __restrict__ mw, const float* __restrict__ mb,
                      float* __restrict__ qkv, float* __restrict__ mkv) {
    int idx = blockIdx.x * blockDim.x + threadIdx.x;
    if (idx >= NB * 10 * SS) return;
    int s = idx % SS;
    int g = (idx / SS) % 10;
    int n = idx / (10 * SS);

    float reg[HD];
    const float* src = ((g < 6) ? h : m) + (size_t)n * HD * SS + s;
#pragma unroll
    for (int ic = 0; ic < HD; ++ic) reg[ic] = src[ic * SS];

    if (g < 6) {
        float* dst = &qkv[((size_t)n * SS + s) * 48 + g * 8];
#pragma unroll
        for (int j = 0; j < 8; ++j) {
            const float* wr = &hw[(g * 8 + j) * HD];
            float a = hb[g * 8 + j];
#pragma unroll
            for (int ic = 0; ic < HD; ++ic) a += reg[ic] * wr[ic];
            dst[j] = a;
        }
    } else {
        int gg = g - 6;
        float* dst = &mkv[((size_t)n * SS + s) * 32 + gg * 8];
#pragma unroll
        for (int j = 0; j < 8; ++j) {
            const float* wr = &mw[(gg * 8 + j) * HD];
            float a = mb[gg * 8 + j];
#pragma unroll
            for (int ic = 0; ic < HD; ++ic) a += reg[ic] * wr[ic];
            dst[j] = a;
        }
    }
}

#define LOAD16(dst, srcp) do {                       \
    float4 _a = ((const float4*)(srcp))[0];          \
    float4 _b = ((const float4*)(srcp))[1];          \
    float4 _c = ((const float4*)(srcp))[2];          \
    float4 _d = ((const float4*)(srcp))[3];          \
    dst[0]=_a.x; dst[1]=_a.y; dst[2]=_a.z; dst[3]=_a.w;   \
    dst[4]=_b.x; dst[5]=_b.y; dst[6]=_b.z; dst[7]=_b.w;   \
    dst[8]=_c.x; dst[9]=_c.y; dst[10]=_c.z; dst[11]=_c.w; \
    dst[12]=_d.x; dst[13]=_d.y; dst[14]=_d.z; dst[15]=_d.w; } while(0)

// ---------------- dual spatial attention + z 1x1, fused ----------------
// block: 32 s-rows x 8 t-partials; grid (36 s-chunks, 16 n)
__global__ __launch_bounds__(256) void k_attn(
    const float* __restrict__ qkv, const float* __restrict__ mkv,
    const float* __restrict__ zw, const float* __restrict__ zb,
    float* __restrict__ Z)
{
    __shared__ float red[32][8][38];  // [m,l,o[16]] x2 = 36 (+2 pad)
    const int n = blockIdx.y;
    const int row = threadIdx.x % 32;
    const int part = threadIdx.x / 32;
    const int s = blockIdx.x * 32 + row;

    float q[16];
    LOAD16(q, &qkv[((size_t)n * SS + s) * 48]);

    float mh = -1e30f, lh = 0.f, oh[16];
    float mm = -1e30f, lm = 0.f, om[16];
#pragma unroll
    for (int j = 0; j < 16; ++j) { oh[j] = 0.f; om[j] = 0.f; }

    const float* kvbase = &qkv[(size_t)n * SS * 48];
    const float* mbase  = &mkv[(size_t)n * SS * 32];
    const int t0 = part * 144, t1 = t0 + 144;

    for (int tt = t0; tt < t1; ++tt) {
        float kk[16], vv[16];
        // h-attention
        LOAD16(kk, kvbase + tt * 48 + 16);
        LOAD16(vv, kvbase + tt * 48 + 32);
        float d = 0.f;
#pragma unroll
        for (int j = 0; j < 16; ++j) d += q[j] * kk[j];
        d *= 0.25f;
        float mn = fmaxf(mh, d);
        float eo = __expf(mh - mn);
        float ex = __expf(d - mn);
        lh = lh * eo + ex;
#pragma unroll
        for (int j = 0; j < 16; ++j) oh[j] = oh[j] * eo + ex * vv[j];
        mh = mn;
        // m-attention
        LOAD16(kk, mbase + tt * 32);
        LOAD16(vv, mbase + tt * 32 + 16);
        float d2 = 0.f;
#pragma unroll
        for (int j = 0; j < 16; ++j) d2 += q[j] * kk[j];
        d2 *= 0.25f;
        float mn2 = fmaxf(mm, d2);
        float eo2 = __expf(mm - mn2);
        float ex2 = __expf(d2 - mn2);
        lm = lm * eo2 + ex2;
#pragma unroll
        for (int j = 0; j < 16; ++j) om[j] = om[j] * eo2 + ex2 * vv[j];
        mm = mn2;
    }

    float* rp = red[row][part];
    rp[0] = mh; rp[1] = lh;
#pragma unroll
    for (int j = 0; j < 16; ++j) rp[2 + j] = oh[j];
    rp[18] = mm; rp[19] = lm;
#pragma unroll
    for (int j = 0; j < 16; ++j) rp[20 + j] = om[j];
    __syncthreads();

    for (int off = 4; off >= 1; off >>= 1) {
        if (part < off) {
            float* a = red[row][part];
            float* bq = red[row][part + off];
            {
                float ma = a[0], mb_ = bq[0];
                float mn = fmaxf(ma, mb_);
                float ea = __expf(ma - mn), eb = __expf(mb_ - mn);
                a[0] = mn; a[1] = a[1] * ea + bq[1] * eb;
#pragma unroll
                for (int j = 0; j < 16; ++j) a[2 + j] = a[2 + j] * ea + bq[2 + j] * eb;
            }
            {
                float ma = a[18], mb_ = bq[18];
                float mn = fmaxf(ma, mb_);
                float ea = __expf(ma - mn), eb = __expf(mb_ - mn);
                a[18] = mn; a[19] = a[19] * ea + bq[19] * eb;
#pragma unroll
                for (int j = 0; j < 16; ++j) a[20 + j] = a[20 + j] * ea + bq[20 + j] * eb;
            }
        }
        __syncthreads();
    }

    // fused z = z_w @ [Zh;Zm] + z_b ; each partial-thread does 2 channels
    const float* rp0 = red[row][0];
    float ilh = 1.f / rp0[1];
    float ilm = 1.f / rp0[19];
#pragma unroll
    for (int zc2 = 0; zc2 < 2; ++zc2) {
        int zc = part * 2 + zc2;
        const float* zr = &zw[zc * 32];
        float accz = zb[zc];
#pragma unroll
        for (int j = 0; j < 16; ++j) accz += zr[j] * (rp0[2 + j] * ilh);
#pragma unroll
        for (int j = 0; j < 16; ++j) accz += zr[16 + j] * (rp0[20 + j] * ilm);
        Z[((size_t)n * DATT + zc) * SS + s] = accz;
    }
}

// ---------------- SA memory gates ----------------
__global__ void k_sa_gates(const float* __restrict__ iog, float* __restrict__ m,
                           float* __restrict__ h) {
    int i = blockIdx.x * blockDim.x + threadIdx.x;
    if (i >= NB * HD * SS) return;
    int s = i % SS;
    int ch = (i / SS) % HD;
    int n = i / (HD * SS);
    const float* ib = iog + (size_t)n * 3 * HD * SS;
    float si = ib[ch * SS + s];
    float sg = ib[(HD + ch) * SS + s];
    float so = ib[(2 * HD + ch) * SS + s];
    si = sigmoidf_(si);
    sg = tanhf(sg);
    float mn = si * sg + (1.f - si) * m[i];
    m[i] = mn;
    h[i] = sigmoidf_(so) * mn;
}

// ---------------- out 1x1 conv (64 -> 2), writes into d_out[t] ----------------
__global__ void k_out(const float* __restrict__ h, const float* __restrict__ ow,
                      const float* __restrict__ ob, float* __restrict__ outbuf, int t) {
    int idx = blockIdx.x * blockDim.x + threadIdx.x;
    if (idx >= NB * SS) return;
    int s = idx % SS;
    int n = idx / SS;
    float reg[HD];
    const float* src = h + (size_t)n * HD * SS + s;
#pragma unroll
    for (int ic = 0; ic < HD; ++ic) reg[ic] = src[ic * SS];
#pragma unroll
    for (int cc = 0; cc < NCOUT; ++cc) {
        const float* wr = &ow[cc * HD];
        float a = ob[cc];
#pragma unroll
        for (int ic = 0; ic < HD; ++ic) a += reg[ic] * wr[ic];
        outbuf[(((size_t)n * TSTEPS + t) * NCOUT + cc) * SS + s] = a;
    }
}

// ---------------- nino prediction ----------------
__global__ void k_nino(const float* __restrict__ outbuf, float* __restrict__ pred) {
    int tidx = threadIdx.x;
    if (tidx >= 16 * 24) return;
    int j = tidx % 24;
    int n = tidx / 24;
    float acc = 0.f;
    for (int f = j; f < j + 3; ++f) {
        int t = 11 + f;
        const float* p = &outbuf[(((size_t)n * TSTEPS + t) * NCOUT + 0) * SS];
        float sloc = 0.f;
        for (int y = 10; y <= 12; ++y)
            for (int x = 19; x <= 29; ++x)
                sloc += p[y * WW + x];
        acc += sloc * (1.f / 33.f);
    }
    pred[n * 24 + j] = acc * (1.f / 3.f);
}

extern "C" void kernel_launch(void* const* d_in, const int* in_sizes, int n_in,
                              void* d_out, int out_size, void* d_ws, size_t ws_size,
                              hipStream_t stream) {
    const float* x      = (const float*)d_in[0];
    const float* conv_w = (const float*)d_in[1];
    const float* conv_b = (const float*)d_in[2];
    const float* h_w    = (const float*)d_in[3];
    const float* h_b    = (const float*)d_in[4];
    const float* m_w    = (const float*)d_in[5];
    const float* m_b    = (const float*)d_in[6];
    const float* z_w    = (const float*)d_in[7];
    const float* z_b    = (const float*)d_in[8];
    const float* o_w    = (const float*)d_in[9];
    const float* o_b    = (const float*)d_in[10];
    const float* out_w  = (const float*)d_in[11];
    const float* out_b  = (const float*)d_in[12];

    float* ws   = (float*)d_ws;
    float* h    = ws + OFF_H;
    float* c    = ws + OFF_C;
    float* m    = ws + OFF_M;
    float* feed = ws + OFF_FEED;
    float* comb = ws + OFF_COMB;
    float* qkv  = ws + OFF_QKV;
    float* mkv  = ws + OFF_MKV;
    float* Z    = ws + OFF_Z;
    float* iog  = ws + OFF_IOG;
    float* outp = (float*)d_out;

    // zero h, c, m  (3 * 1179648 floats = 884736 float4)
    k_zero<<<3456, 256, 0, stream>>>(ws, 884736);

    for (int t = 0; t < TSTEPS; ++t) {
        k_feed<<<216, 256, 0, stream>>>(x, outp, feed, t);
        k_conv3x3<<<dim3(48, 32), 192, 0, stream>>>(feed, 3, h, HD, conv_w, conv_b,
                                                    comb, 4 * HD);
        k_lstm_gates<<<4608, 256, 0, stream>>>(comb, c, h);
        k_qkv<<<720, 256, 0, stream>>>(h, m, h_w, h_b, m_w, m_b, qkv, mkv);
        k_attn<<<dim3(36, 16), 256, 0, stream>>>(qkv, mkv, z_w, z_b, Z);
        k_conv3x3<<<dim3(48, 24), 192, 0, stream>>>(Z, DATT, h, HD, o_w, o_b,
                                                    iog, 3 * HD);
        k_sa_gates<<<4608, 256, 0, stream>>>(iog, m, h);
        k_out<<<72, 256, 0, stream>>>(h, out_w, out_b, outp, t);
    }
    k_nino<<<1, 384, 0, stream>>>(outp, outp + (size_t)NB * TSTEPS * NCOUT * SS);
}

// Round 2
// 16443.690 us; speedup vs baseline: 1.6546x; 1.6546x over previous
//
#include <hip/hip_runtime.h>
#include <math.h>

#define HD 64
#define DATT 16
#define NCIN 3
#define NCOUT 2
#define HH 24
#define WW 48
#define SS (HH*WW)          // 1152
#define NB 16
#define TSTEPS 37
#define INPUT_FRAMES 12

// padded spatial plane: rows p = y+1 (y in -1..24), cols q = x+1 (x in -1..48)
// row stride 52 (52 floats = 13 float4, so every row is 16B-aligned)
#define PR 26
#define PC 52
#define PHW (PR*PC)         // 1352

// ---------------- workspace layout (floats) ----------------
#define OFF_H     0                      // 16*64*1352 = 1384448 (padded)
#define OFF_C     1384448                // 16*64*1152 (unpadded)
#define OFF_M     2564096                // 16*64*1152 (unpadded)
#define OFF_FEED  3743744                // 16*3*1352 (padded)
#define OFF_Z     3808640                // 16*16*1352 (padded)
#define ZERO_END  4154752                // everything above zeroed each launch
#define OFF_COMB  4154752                // 16*256*1152 = 4718592
#define OFF_QKV   4154752                // aliases comb (dead after lstm gates)
#define OFF_MKV   5039488                // qkv + 884736
#define OFF_IOG   8873344                // comb + 4718592
// end = 12412288 floats = 49.6 MB

__device__ __forceinline__ float sigmoidf_(float x) {
    return 1.0f / (1.0f + __expf(-x));
}

// ---------------- zero padded state ----------------
__global__ void k_zero(float* __restrict__ p, int n4) {
    int i = blockIdx.x * blockDim.x + threadIdx.x;
    if (i < n4) ((float4*)p)[i] = make_float4(0.f, 0.f, 0.f, 0.f);
}

// ---------------- feed selection (writes padded interior) ----------------
__global__ void k_feed(const float* __restrict__ x, const float* __restrict__ outbuf,
                       float* __restrict__ feed, int t) {
    int i = blockIdx.x * blockDim.x + threadIdx.x;
    if (i >= NB * 3 * SS) return;
    int s = i % SS;
    int ch = (i / SS) % 3;
    int n = i / (3 * SS);
    int y = s / WW, xx = s % WW;
    float v;
    if (t < INPUT_FRAMES || ch == 2) {
        v = x[(((n * TSTEPS + t) * HH + y) * WW + xx) * NCIN + ch];
    } else {
        v = outbuf[(((n * TSTEPS + (t - 1)) * NCOUT + ch) * HH + y) * WW + xx];
    }
    feed[((size_t)(n * 3 + ch) * PR + (y + 1)) * PC + (xx + 1)] = v;
}

// ---------------- generic 3x3 conv, pad=1, fp32, padded inputs ----------------
// in1/in2 are PADDED [C][26][52]; out is unpadded NCHW
// grid: (16n * 3 row-tiles, OC/8); block 192 = 24 col-groups (2 px) x 8 rows
__global__ __launch_bounds__(192) void k_conv3x3(
    const float* __restrict__ in1, int C1,
    const float* __restrict__ in2, int C2,
    const float* __restrict__ w, const float* __restrict__ b,
    float* __restrict__ out, int OC)
{
    __shared__ __align__(16) float lds_patch[8 * 520];  // 8 ch x 10 rows x 52 cols
    __shared__ __align__(16) float lds_w[80 * 72];      // [c][kt][ocl]

    const int bx = blockIdx.x;
    const int n = bx / 3, tile = bx % 3;
    const int ocg = blockIdx.y;
    const int C = C1 + C2;
    const int nchunk = (C + 7) / 8;
    const int tid = threadIdx.x;
    const int y0 = tile * 8;

    // stage all weights for this oc-group (zero-padded past C)
    const int wtot = nchunk * 8 * 72;
    for (int i = tid; i < wtot; i += 192) {
        int ocl = i % 8;
        int kt  = (i / 8) % 9;
        int c   = i / 72;
        float val = 0.f;
        if (c < C) val = w[((ocg * 8 + ocl) * C + c) * 9 + kt];
        lds_w[i] = val;
    }

    const float4* in1_4 = (const float4*)(in1 + (size_t)n * C1 * PHW);
    const float4* in2_4 = (const float4*)(in2 + (size_t)n * C2 * PHW);

    // per-chunk patch: 8 ch x 130 float4 (10 rows x 13 f4) = 1040 f4
    float4 pf[6];
    auto load_chunk = [&](int chunk) {
#pragma unroll
        for (int k = 0; k < 6; ++k) {
            int i = tid + 192 * k;
            if (i < 1040) {
                int c_l = i / 130;
                int rem = i - c_l * 130;
                int c = chunk * 8 + c_l;
                float4 v = make_float4(0.f, 0.f, 0.f, 0.f);
                if (c < C) {
                    v = (c < C1) ? in1_4[(c * PR + y0) * 13 + rem]
                                 : in2_4[((c - C1) * PR + y0) * 13 + rem];
                }
                pf[k] = v;
            }
        }
    };

    const int cg = tid % 24;
    const int ty = tid / 24;
    const int x0 = cg * 2;          // output x0, x0+1 ; reads padded cols x0..x0+3
    const int y_out = y0 + ty;

    float acc[16];
#pragma unroll
    for (int j = 0; j < 16; ++j) acc[j] = 0.f;

    load_chunk(0);
    for (int chunk = 0; chunk < nchunk; ++chunk) {
        __syncthreads();
#pragma unroll
        for (int k = 0; k < 6; ++k) {
            int i = tid + 192 * k;
            if (i < 1040) ((float4*)lds_patch)[i] = pf[k];
        }
        if (chunk + 1 < nchunk) load_chunk(chunk + 1);
        __syncthreads();

#pragma unroll 2
        for (int icl = 0; icl < 8; ++icl) {
            const int c = chunk * 8 + icl;
            const float* wb_ = &lds_w[c * 72];
            const float* pr = &lds_patch[icl * 520 + ty * PC + x0];
#pragma unroll
            for (int ky = 0; ky < 3; ++ky) {
                const float* r = pr + ky * PC;
                float i0 = r[0], i1 = r[1], i2 = r[2], i3 = r[3];
                const float* wk = wb_ + ky * 24;
#pragma unroll
                for (int kx = 0; kx < 3; ++kx) {
                    float va = (kx == 0) ? i0 : ((kx == 1) ? i1 : i2);
                    float vb = (kx == 0) ? i1 : ((kx == 1) ? i2 : i3);
                    const float4 wa  = *(const float4*)(wk + kx * 8);
                    const float4 wb4 = *(const float4*)(wk + kx * 8 + 4);
                    acc[0]  += va * wa.x;  acc[1]  += va * wa.y;
                    acc[2]  += va * wa.z;  acc[3]  += va * wa.w;
                    acc[4]  += va * wb4.x; acc[5]  += va * wb4.y;
                    acc[6]  += va * wb4.z; acc[7]  += va * wb4.w;
                    acc[8]  += vb * wa.x;  acc[9]  += vb * wa.y;
                    acc[10] += vb * wa.z;  acc[11] += vb * wa.w;
                    acc[12] += vb * wb4.x; acc[13] += vb * wb4.y;
                    acc[14] += vb * wb4.z; acc[15] += vb * wb4.w;
                }
            }
        }
    }

#pragma unroll
    for (int j = 0; j < 8; ++j) {
        int oc = ocg * 8 + j;
        float bv = b[oc];
        float2 o2 = make_float2(acc[j] + bv, acc[8 + j] + bv);
        *(float2*)&out[((n * OC + oc) * HH + y_out) * WW + x0] = o2;
    }
}

// ---------------- ConvLSTM gates (h written padded) ----------------
__global__ void k_lstm_gates(const float* __restrict__ comb, float* __restrict__ c,
                             float* __restrict__ h) {
    int i = blockIdx.x * blockDim.x + threadIdx.x;
    if (i >= NB * HD * SS) return;
    int s = i % SS;
    int ch = (i / SS) % HD;
    int n = i / (HD * SS);
    const float* cb = comb + (size_t)n * 4 * HD * SS;
    float ci = cb[(ch) * SS + s];
    float cf = cb[(ch + HD) * SS + s];
    float co = cb[(ch + 2 * HD) * SS + s];
    float cg = cb[(ch + 3 * HD) * SS + s];
    float ig = sigmoidf_(ci);
    float fg = sigmoidf_(cf);
    float og = sigmoidf_(co);
    float gg = tanhf(cg);
    float cn = fg * c[i] + ig * gg;
    c[i] = cn;
    int y = s / WW, x = s % WW;
    h[((size_t)(n * HD + ch) * PR + (y + 1)) * PC + (x + 1)] = og * tanhf(cn);
}

// ---------------- 1x1 q/k/v + mk/mv projections ----------------
// grid (72, 10): blockIdx.y = group g (0..5 from h, 6..9 from m), weights in LDS
__global__ __launch_bounds__(256) void k_qkv(
    const float* __restrict__ h, const float* __restrict__ m,
    const float* __restrict__ hw, const float* __restrict__ hb,
    const float* __restrict__ mw, const float* __restrict__ mb,
    float* __restrict__ qkv, float* __restrict__ mkv) {
    __shared__ float lw[512];
    __shared__ float lb[8];
    const int g = blockIdx.y;
    const int tid = threadIdx.x;
    const float* wsrc = (g < 6) ? (hw + g * 512) : (mw + (g - 6) * 512);
    const float* bsrc = (g < 6) ? (hb + g * 8) : (mb + (g - 6) * 8);
    for (int i = tid; i < 512; i += 256) lw[i] = wsrc[i];
    if (tid < 8) lb[tid] = bsrc[tid];
    __syncthreads();

    int idx = blockIdx.x * 256 + tid;
    int s = idx % SS;
    int n = idx / SS;
    int y = s / WW, x = s % WW;

    float reg[HD];
    if (g < 6) {
        const float* src = h + (size_t)n * HD * PHW + (y + 1) * PC + (x + 1);
#pragma unroll
        for (int ic = 0; ic < HD; ++ic) reg[ic] = src[ic * PHW];
    } else {
        const float* src = m + (size_t)n * HD * SS + s;
#pragma unroll
        for (int ic = 0; ic < HD; ++ic) reg[ic] = src[ic * SS];
    }

    float* dst = (g < 6) ? &qkv[((size_t)n * SS + s) * 48 + g * 8]
                         : &mkv[((size_t)n * SS + s) * 32 + (g - 6) * 8];
#pragma unroll
    for (int j = 0; j < 8; ++j) {
        const float* wr = &lw[j * HD];
        float a = lb[j];
#pragma unroll
        for (int ic = 0; ic < HD; ++ic) a += reg[ic] * wr[ic];
        dst[j] = a;
    }
}

#define LOAD16(dst, srcp) do {                       \
    float4 _a = ((const float4*)(srcp))[0];          \
    float4 _b = ((const float4*)(srcp))[1];          \
    float4 _c = ((const float4*)(srcp))[2];          \
    float4 _d = ((const float4*)(srcp))[3];          \
    dst[0]=_a.x; dst[1]=_a.y; dst[2]=_a.z; dst[3]=_a.w;   \
    dst[4]=_b.x; dst[5]=_b.y; dst[6]=_b.z; dst[7]=_b.w;   \
    dst[8]=_c.x; dst[9]=_c.y; dst[10]=_c.z; dst[11]=_c.w; \
    dst[12]=_d.x; dst[13]=_d.y; dst[14]=_d.z; dst[15]=_d.w; } while(0)

// ---------------- dual spatial attention + z 1x1, LDS-tiled KV ----------------
// block: 32 s-rows x 8 t-partials; grid (36 s-chunks, 16 n)
// KV staged in LDS in tiles of 144 t; reduction scratch aliases the KV area.
__global__ __launch_bounds__(256) void k_attn(
    const float* __restrict__ qkv, const float* __restrict__ mkv,
    const float* __restrict__ zw, const float* __restrict__ zb,
    float* __restrict__ Z)
{
    __shared__ __align__(16) float smem[9728];  // kv tile: 144*64=9216 ; red: 32*8*38=9728
    const int n = blockIdx.y;
    const int tid = threadIdx.x;
    const int row = tid % 32;
    const int part = tid / 32;
    const int s = blockIdx.x * 32 + row;

    float q[16];
    LOAD16(q, &qkv[((size_t)n * SS + s) * 48]);

    float mh = -1e30f, lh = 0.f, oh[16];
    float mm = -1e30f, lm = 0.f, om[16];
#pragma unroll
    for (int j = 0; j < 16; ++j) { oh[j] = 0.f; om[j] = 0.f; }

    const float4* qkv4 = (const float4*)qkv + (size_t)n * SS * 12;
    const float4* mkv4 = (const float4*)mkv + (size_t)n * SS * 8;

    for (int tile = 0; tile < 8; ++tile) {
        __syncthreads();
        // stage 144 t x 64 floats: [t][hk16|hv16|mk16|mv16]
#pragma unroll
        for (int k = 0; k < 9; ++k) {
            int j = tid + 256 * k;
            int t_loc = j >> 4, f = j & 15;
            int t = tile * 144 + t_loc;
            float4 v;
            if (f < 8) v = qkv4[t * 12 + 4 + f];
            else       v = mkv4[t * 8 + (f - 8)];
            ((float4*)smem)[j] = v;
        }
        __syncthreads();

        const int t0 = part * 18;
        for (int tl = t0; tl < t0 + 18; ++tl) {
            const float* kvb = &smem[tl * 64];
            float kk[16], vv[16];
            LOAD16(kk, kvb);
            LOAD16(vv, kvb + 16);
            float d = 0.f;
#pragma unroll
            for (int j = 0; j < 16; ++j) d += q[j] * kk[j];
            d *= 0.25f;
            float mn = fmaxf(mh, d);
            float eo = __expf(mh - mn);
            float ex = __expf(d - mn);
            lh = lh * eo + ex;
#pragma unroll
            for (int j = 0; j < 16; ++j) oh[j] = oh[j] * eo + ex * vv[j];
            mh = mn;

            LOAD16(kk, kvb + 32);
            LOAD16(vv, kvb + 48);
            float d2 = 0.f;
#pragma unroll
            for (int j = 0; j < 16; ++j) d2 += q[j] * kk[j];
            d2 *= 0.25f;
            float mn2 = fmaxf(mm, d2);
            float eo2 = __expf(mm - mn2);
            float ex2 = __expf(d2 - mn2);
            lm = lm * eo2 + ex2;
#pragma unroll
            for (int j = 0; j < 16; ++j) om[j] = om[j] * eo2 + ex2 * vv[j];
            mm = mn2;
        }
    }

    __syncthreads();   // done reading kv area; reuse as reduction scratch
    float* rp = &smem[(row * 8 + part) * 38];
    rp[0] = mh; rp[1] = lh;
#pragma unroll
    for (int j = 0; j < 16; ++j) rp[2 + j] = oh[j];
    rp[18] = mm; rp[19] = lm;
#pragma unroll
    for (int j = 0; j < 16; ++j) rp[20 + j] = om[j];
    __syncthreads();

    for (int off = 4; off >= 1; off >>= 1) {
        if (part < off) {
            float* a = &smem[(row * 8 + part) * 38];
            float* bq = &smem[(row * 8 + part + off) * 38];
            {
                float ma = a[0], mb_ = bq[0];
                float mn = fmaxf(ma, mb_);
                float ea = __expf(ma - mn), eb = __expf(mb_ - mn);
                a[0] = mn; a[1] = a[1] * ea + bq[1] * eb;
#pragma unroll
                for (int j = 0; j < 16; ++j) a[2 + j] = a[2 + j] * ea + bq[2 + j] * eb;
            }
            {
                float ma = a[18], mb_ = bq[18];
                float mn = fmaxf(ma, mb_);
                float ea = __expf(ma - mn), eb = __expf(mb_ - mn);
                a[18] = mn; a[19] = a[19] * ea + bq[19] * eb;
#pragma unroll
                for (int j = 0; j < 16; ++j) a[20 + j] = a[20 + j] * ea + bq[20 + j] * eb;
            }
        }
        __syncthreads();
    }

    // fused z = z_w @ [Zh;Zm] + z_b ; each partial-thread does 2 channels
    const float* rp0 = &smem[(row * 8) * 38];
    float ilh = 1.f / rp0[1];
    float ilm = 1.f / rp0[19];
    int y = s / WW, x = s % WW;
#pragma unroll
    for (int zc2 = 0; zc2 < 2; ++zc2) {
        int zc = part * 2 + zc2;
        const float* zr = &zw[zc * 32];
        float accz = zb[zc];
#pragma unroll
        for (int j = 0; j < 16; ++j) accz += zr[j] * (rp0[2 + j] * ilh);
#pragma unroll
        for (int j = 0; j < 16; ++j) accz += zr[16 + j] * (rp0[20 + j] * ilm);
        Z[((size_t)(n * DATT + zc) * PR + (y + 1)) * PC + (x + 1)] = accz;
    }
}

// ---------------- SA memory gates (h written padded) ----------------
__global__ void k_sa_gates(const float* __restrict__ iog, float* __restrict__ m,
                           float* __restrict__ h) {
    int i = blockIdx.x * blockDim.x + threadIdx.x;
    if (i >= NB * HD * SS) return;
    int s = i % SS;
    int ch = (i / SS) % HD;
    int n = i / (HD * SS);
    const float* ib = iog + (size_t)n * 3 * HD * SS;
    float si = ib[ch * SS + s];
    float sg = ib[(HD + ch) * SS + s];
    float so = ib[(2 * HD + ch) * SS + s];
    si = sigmoidf_(si);
    sg = tanhf(sg);
    float mn = si * sg + (1.f - si) * m[i];
    m[i] = mn;
    int y = s / WW, x = s % WW;
    h[((size_t)(n * HD + ch) * PR + (y + 1)) * PC + (x + 1)] = sigmoidf_(so) * mn;
}

// ---------------- out 1x1 conv (64 -> 2), padded h -> d_out[t] ----------------
__global__ void k_out(const float* __restrict__ h, const float* __restrict__ ow,
                      const float* __restrict__ ob, float* __restrict__ outbuf, int t) {
    int idx = blockIdx.x * blockDim.x + threadIdx.x;
    if (idx >= NB * SS) return;
    int s = idx % SS;
    int n = idx / SS;
    int y = s / WW, x = s % WW;
    float reg[HD];
    const float* src = h + (size_t)n * HD * PHW + (y + 1) * PC + (x + 1);
#pragma unroll
    for (int ic = 0; ic < HD; ++ic) reg[ic] = src[ic * PHW];
#pragma unroll
    for (int cc = 0; cc < NCOUT; ++cc) {
        const float* wr = &ow[cc * HD];
        float a = ob[cc];
#pragma unroll
        for (int ic = 0; ic < HD; ++ic) a += reg[ic] * wr[ic];
        outbuf[(((size_t)n * TSTEPS + t) * NCOUT + cc) * SS + s] = a;
    }
}

// ---------------- nino prediction ----------------
__global__ void k_nino(const float* __restrict__ outbuf, float* __restrict__ pred) {
    int tidx = threadIdx.x;
    if (tidx >= 16 * 24) return;
    int j = tidx % 24;
    int n = tidx / 24;
    float acc = 0.f;
    for (int f = j; f < j + 3; ++f) {
        int t = 11 + f;
        const float* p = &outbuf[(((size_t)n * TSTEPS + t) * NCOUT + 0) * SS];
        float sloc = 0.f;
        for (int y = 10; y <= 12; ++y)
            for (int x = 19; x <= 29; ++x)
                sloc += p[y * WW + x];
        acc += sloc * (1.f / 33.f);
    }
    pred[n * 24 + j] = acc * (1.f / 3.f);
}

extern "C" void kernel_launch(void* const* d_in, const int* in_sizes, int n_in,
                              void* d_out, int out_size, void* d_ws, size_t ws_size,
                              hipStream_t stream) {
    const float* x      = (const float*)d_in[0];
    const float* conv_w = (const float*)d_in[1];
    const float* conv_b = (const float*)d_in[2];
    const float* h_w    = (const float*)d_in[3];
    const float* h_b    = (const float*)d_in[4];
    const float* m_w    = (const float*)d_in[5];
    const float* m_b    = (const float*)d_in[6];
    const float* z_w    = (const float*)d_in[7];
    const float* z_b    = (const float*)d_in[8];
    const float* o_w    = (const float*)d_in[9];
    const float* o_b    = (const float*)d_in[10];
    const float* out_w  = (const float*)d_in[11];
    const float* out_b  = (const float*)d_in[12];

    float* ws   = (float*)d_ws;
    float* h    = ws + OFF_H;
    float* c    = ws + OFF_C;
    float* m    = ws + OFF_M;
    float* feed = ws + OFF_FEED;
    float* comb = ws + OFF_COMB;
    float* qkv  = ws + OFF_QKV;
    float* mkv  = ws + OFF_MKV;
    float* Z    = ws + OFF_Z;
    float* iog  = ws + OFF_IOG;
    float* outp = (float*)d_out;

    // zero h (padded), c, m, feed (padded), Z (padded): 4154752 floats = 1038688 f4
    k_zero<<<4058, 256, 0, stream>>>(ws, 1038688);

    for (int t = 0; t < TSTEPS; ++t) {
        k_feed<<<216, 256, 0, stream>>>(x, outp, feed, t);
        k_conv3x3<<<dim3(48, 32), 192, 0, stream>>>(feed, 3, h, HD, conv_w, conv_b,
                                                    comb, 4 * HD);
        k_lstm_gates<<<4608, 256, 0, stream>>>(comb, c, h);
        k_qkv<<<dim3(72, 10), 256, 0, stream>>>(h, m, h_w, h_b, m_w, m_b, qkv, mkv);
        k_attn<<<dim3(36, 16), 256, 0, stream>>>(qkv, mkv, z_w, z_b, Z);
        k_conv3x3<<<dim3(48, 24), 192, 0, stream>>>(Z, DATT, h, HD, o_w, o_b,
                                                    iog, 3 * HD);
        k_sa_gates<<<4608, 256, 0, stream>>>(iog, m, h);
        k_out<<<72, 256, 0, stream>>>(h, out_w, out_b, outp, t);
    }
    k_nino<<<1, 384, 0, stream>>>(outp, outp + (size_t)NB * TSTEPS * NCOUT * SS);
}

// Round 5
// 15197.444 us; speedup vs baseline: 1.7903x; 1.0820x over previous
//
#include <hip/hip_runtime.h>
#include <math.h>

#define HD 64
#define DATT 16
#define NCIN 3
#define NCOUT 2
#define HH 24
#define WW 48
#define SS (HH*WW)          // 1152
#define NB 16
#define TSTEPS 37
#define INPUT_FRAMES 12

// padded spatial plane: rows p = y+1 (y in -1..24), cols q = x+1 (x in -1..48)
// row stride 52 (52 floats = 13 float4, so every row is 16B-aligned)
#define PR 26
#define PC 52
#define PHW (PR*PC)         // 1352

// ---------------- workspace layout (floats) ----------------
#define OFF_H     0                      // 16*64*1352 = 1384448 (padded)
#define OFF_C     1384448                // 16*64*1152 (unpadded)
#define OFF_M     2564096                // 16*64*1152 (unpadded)
#define OFF_FEED  3743744                // 16*3*1352 (padded)
#define OFF_Z     3808640                // 16*16*1352 (padded)
#define ZERO_END  4154752                // everything above zeroed each launch
#define OFF_COMB  4154752                // 16*256*1152 = 4718592
#define OFF_QKV   4154752                // aliases comb (dead after lstm gates)
#define OFF_MKV   5039488                // qkv + 884736
#define OFF_IOG   8873344                // comb + 4718592
#define OFF_W2G   12412288               // 32*72*9*8 = 165888  (gate conv weights, reordered)
#define OFF_W3G   12578176               // 24*80*9*8 = 138240  (out conv weights, reordered)
// end = 12716416 floats = 50.9 MB

__device__ __forceinline__ float sigmoidf_(float x) {
    return 1.0f / (1.0f + __expf(-x));
}

// ---------------- zero padded state ----------------
__global__ void k_zero(float* __restrict__ p, int n4) {
    int i = blockIdx.x * blockDim.x + threadIdx.x;
    if (i < n4) ((float4*)p)[i] = make_float4(0.f, 0.f, 0.f, 0.f);
}

// ---------------- weight reorder: conv_w -> w2g [ocg(32)][c(72)][kt(9)][ocl(8)] ----------------
// w2g[((ocg*72 + c)*9 + kt)*8 + ocl] = cw[(ocg*8+ocl)*603 + c*9 + kt]  (c >= 67 -> 0)
__global__ void k_prep_w2g(const float* __restrict__ cw, float* __restrict__ w2g) {
    int idx = blockIdx.x * blockDim.x + threadIdx.x;
    if (idx >= 165888) return;
    int ocl = idx & 7;
    int kt  = (idx >> 3) % 9;
    int c   = (idx / 72) % 72;
    int ocg = idx / 5184;
    w2g[idx] = (c < 67) ? cw[(ocg * 8 + ocl) * 603 + c * 9 + kt] : 0.f;
}

// ---------------- weight reorder: o_w -> w3g [ocg(24)][c(80)][kt(9)][ocl(8)] ----------------
__global__ void k_prep_w3g(const float* __restrict__ ow, float* __restrict__ w3g) {
    int idx = blockIdx.x * blockDim.x + threadIdx.x;
    if (idx >= 138240) return;
    int ocl = idx & 7;
    int kt  = (idx >> 3) % 9;
    int c   = (idx / 72) % 80;
    int ocg = idx / 5760;
    w3g[idx] = ow[(ocg * 8 + ocl) * 720 + c * 9 + kt];
}

// ---------------- feed selection (writes padded interior) ----------------
__global__ void k_feed(const float* __restrict__ x, const float* __restrict__ outbuf,
                       float* __restrict__ feed, int t) {
    int i = blockIdx.x * blockDim.x + threadIdx.x;
    if (i >= NB * 3 * SS) return;
    int s = i % SS;
    int ch = (i / SS) % 3;
    int n = i / (3 * SS);
    int y = s / WW, xx = s % WW;
    float v;
    if (t < INPUT_FRAMES || ch == 2) {
        v = x[(((n * TSTEPS + t) * HH + y) * WW + xx) * NCIN + ch];
    } else {
        v = outbuf[(((n * TSTEPS + (t - 1)) * NCOUT + ch) * HH + y) * WW + xx];
    }
    feed[((size_t)(n * 3 + ch) * PR + (y + 1)) * PC + (xx + 1)] = v;
}

// ---------------- generic 3x3 conv, pad=1, fp32, padded inputs ----------------
// in1/in2 are PADDED [C][26][52]; out is unpadded NCHW
// w is PRE-REORDERED: [ocg][Cpad][9 kt][8 ocl], Cpad = nchunk*8
// grid: (16n * 3 row-tiles, OC/8); block 192 = 24 col-groups (2 px) x 8 rows
__global__ __launch_bounds__(192) void k_conv3x3(
    const float* __restrict__ in1, int C1,
    const float* __restrict__ in2, int C2,
    const float* __restrict__ w, const float* __restrict__ b,
    float* __restrict__ out, int OC)
{
    __shared__ __align__(16) float lds_patch[8 * 520];  // 8 ch x 10 rows x 52 cols

    const int bx = blockIdx.x;
    const int n = bx / 3, tile = bx % 3;
    const int ocg = blockIdx.y;
    const int C = C1 + C2;
    const int nchunk = (C + 7) / 8;
    const int tid = threadIdx.x;
    const int y0 = tile * 8;

    // block-uniform weight base for this oc-group (pre-reordered, zero-padded past C)
    const float* wg = w + (size_t)ocg * (size_t)(nchunk * 8 * 72);

    const float4* in1_4 = (const float4*)(in1 + (size_t)n * C1 * PHW);
    const float4* in2_4 = (const float4*)(in2 + (size_t)n * C2 * PHW);

    // per-chunk patch: 8 ch x 130 float4 (10 rows x 13 f4) = 1040 f4
    float4 pf[6];
    auto load_chunk = [&](int chunk) {
#pragma unroll
        for (int k = 0; k < 6; ++k) {
            int i = tid + 192 * k;
            if (i < 1040) {
                int c_l = i / 130;
                int rem = i - c_l * 130;
                int c = chunk * 8 + c_l;
                float4 v = make_float4(0.f, 0.f, 0.f, 0.f);
                if (c < C) {
                    v = (c < C1) ? in1_4[(c * PR + y0) * 13 + rem]
                                 : in2_4[((c - C1) * PR + y0) * 13 + rem];
                }
                pf[k] = v;
            }
        }
    };

    const int cg = tid % 24;
    const int ty = tid / 24;
    const int x0 = cg * 2;          // output x0, x0+1 ; reads padded cols x0..x0+3
    const int y_out = y0 + ty;

    float acc[16];
#pragma unroll
    for (int j = 0; j < 16; ++j) acc[j] = 0.f;

    load_chunk(0);
    for (int chunk = 0; chunk < nchunk; ++chunk) {
        __syncthreads();
#pragma unroll
        for (int k = 0; k < 6; ++k) {
            int i = tid + 192 * k;
            if (i < 1040) ((float4*)lds_patch)[i] = pf[k];
        }
        if (chunk + 1 < nchunk) load_chunk(chunk + 1);
        __syncthreads();

#pragma unroll 2
        for (int icl = 0; icl < 8; ++icl) {
            const int c = chunk * 8 + icl;
            const float* wb_ = wg + c * 72;        // [kt][8 ocl], global (uniform)
            const float* pr = &lds_patch[icl * 520 + ty * PC + x0];
#pragma unroll
            for (int ky = 0; ky < 3; ++ky) {
                const float* r = pr + ky * PC;
                float i0 = r[0], i1 = r[1], i2 = r[2], i3 = r[3];
                const float* wk = wb_ + ky * 24;
#pragma unroll
                for (int kx = 0; kx < 3; ++kx) {
                    float va = (kx == 0) ? i0 : ((kx == 1) ? i1 : i2);
                    float vb = (kx == 0) ? i1 : ((kx == 1) ? i2 : i3);
                    const float4 wa  = *(const float4*)(wk + kx * 8);
                    const float4 wb4 = *(const float4*)(wk + kx * 8 + 4);
                    acc[0]  += va * wa.x;  acc[1]  += va * wa.y;
                    acc[2]  += va * wa.z;  acc[3]  += va * wa.w;
                    acc[4]  += va * wb4.x; acc[5]  += va * wb4.y;
                    acc[6]  += va * wb4.z; acc[7]  += va * wb4.w;
                    acc[8]  += vb * wa.x;  acc[9]  += vb * wa.y;
                    acc[10] += vb * wa.z;  acc[11] += vb * wa.w;
                    acc[12] += vb * wb4.x; acc[13] += vb * wb4.y;
                    acc[14] += vb * wb4.z; acc[15] += vb * wb4.w;
                }
            }
        }
    }

#pragma unroll
    for (int j = 0; j < 8; ++j) {
        int oc = ocg * 8 + j;
        float bv = b[oc];
        float2 o2 = make_float2(acc[j] + bv, acc[8 + j] + bv);
        *(float2*)&out[((n * OC + oc) * HH + y_out) * WW + x0] = o2;
    }
}

// ---------------- ConvLSTM gates (h written padded) ----------------
__global__ void k_lstm_gates(const float* __restrict__ comb, float* __restrict__ c,
                             float* __restrict__ h) {
    int i = blockIdx.x * blockDim.x + threadIdx.x;
    if (i >= NB * HD * SS) return;
    int s = i % SS;
    int ch = (i / SS) % HD;
    int n = i / (HD * SS);
    const float* cb = comb + (size_t)n * 4 * HD * SS;
    float ci = cb[(ch) * SS + s];
    float cf = cb[(ch + HD) * SS + s];
    float co = cb[(ch + 2 * HD) * SS + s];
    float cg = cb[(ch + 3 * HD) * SS + s];
    float ig = sigmoidf_(ci);
    float fg = sigmoidf_(cf);
    float og = sigmoidf_(co);
    float gg = tanhf(cg);
    float cn = fg * c[i] + ig * gg;
    c[i] = cn;
    int y = s / WW, x = s % WW;
    h[((size_t)(n * HD + ch) * PR + (y + 1)) * PC + (x + 1)] = og * tanhf(cn);
}

// ---------------- 1x1 q/k/v + mk/mv projections ----------------
// grid (72, 10): blockIdx.y = group g (0..5 from h, 6..9 from m), weights in LDS
__global__ __launch_bounds__(256) void k_qkv(
    const float* __restrict__ h, const float* __restrict__ m,
    const float* __restrict__ hw, const float* __restrict__ hb,
    const float* __restrict__ mw, const float* __restrict__ mb,
    float* __restrict__ qkv, float* __restrict__ mkv) {
    __shared__ float lw[512];
    __shared__ float lb[8];
    const int g = blockIdx.y;
    const int tid = threadIdx.x;
    const float* wsrc = (g < 6) ? (hw + g * 512) : (mw + (g - 6) * 512);
    const float* bsrc = (g < 6) ? (hb + g * 8) : (mb + (g - 6) * 8);
    for (int i = tid; i < 512; i += 256) lw[i] = wsrc[i];
    if (tid < 8) lb[tid] = bsrc[tid];
    __syncthreads();

    int idx = blockIdx.x * 256 + tid;
    int s = idx % SS;
    int n = idx / SS;
    int y = s / WW, x = s % WW;

    float reg[HD];
    if (g < 6) {
        const float* src = h + (size_t)n * HD * PHW + (y + 1) * PC + (x + 1);
#pragma unroll
        for (int ic = 0; ic < HD; ++ic) reg[ic] = src[ic * PHW];
    } else {
        const float* src = m + (size_t)n * HD * SS + s;
#pragma unroll
        for (int ic = 0; ic < HD; ++ic) reg[ic] = src[ic * SS];
    }

    float* dst = (g < 6) ? &qkv[((size_t)n * SS + s) * 48 + g * 8]
                         : &mkv[((size_t)n * SS + s) * 32 + (g - 6) * 8];
#pragma unroll
    for (int j = 0; j < 8; ++j) {
        const float* wr = &lw[j * HD];
        float a = lb[j];
#pragma unroll
        for (int ic = 0; ic < HD; ++ic) a += reg[ic] * wr[ic];
        dst[j] = a;
    }
}

#define LOAD16(dst, srcp) do {                       \
    float4 _a = ((const float4*)(srcp))[0];          \
    float4 _b = ((const float4*)(srcp))[1];          \
    float4 _c = ((const float4*)(srcp))[2];          \
    float4 _d = ((const float4*)(srcp))[3];          \
    dst[0]=_a.x; dst[1]=_a.y; dst[2]=_a.z; dst[3]=_a.w;   \
    dst[4]=_b.x; dst[5]=_b.y; dst[6]=_b.z; dst[7]=_b.w;   \
    dst[8]=_c.x; dst[9]=_c.y; dst[10]=_c.z; dst[11]=_c.w; \
    dst[12]=_d.x; dst[13]=_d.y; dst[14]=_d.z; dst[15]=_d.w; } while(0)

// ---------------- dual spatial attention + z 1x1, LDS-tiled KV ----------------
// block: 32 s-rows x 8 t-partials; grid (36 s-chunks, 16 n)
// KV staged in LDS in tiles of 144 t; reduction scratch aliases the KV area.
__global__ __launch_bounds__(256) void k_attn(
    const float* __restrict__ qkv, const float* __restrict__ mkv,
    const float* __restrict__ zw, const float* __restrict__ zb,
    float* __restrict__ Z)
{
    __shared__ __align__(16) float smem[9728];  // kv tile: 144*64=9216 ; red: 32*8*38=9728
    const int n = blockIdx.y;
    const int tid = threadIdx.x;
    const int row = tid % 32;
    const int part = tid / 32;
    const int s = blockIdx.x * 32 + row;

    float q[16];
    LOAD16(q, &qkv[((size_t)n * SS + s) * 48]);

    float mh = -1e30f, lh = 0.f, oh[16];
    float mm = -1e30f, lm = 0.f, om[16];
#pragma unroll
    for (int j = 0; j < 16; ++j) { oh[j] = 0.f; om[j] = 0.f; }

    const float4* qkv4 = (const float4*)qkv + (size_t)n * SS * 12;
    const float4* mkv4 = (const float4*)mkv + (size_t)n * SS * 8;

    for (int tile = 0; tile < 8; ++tile) {
        __syncthreads();
        // stage 144 t x 64 floats: [t][hk16|hv16|mk16|mv16]
#pragma unroll
        for (int k = 0; k < 9; ++k) {
            int j = tid + 256 * k;
            int t_loc = j >> 4, f = j & 15;
            int t = tile * 144 + t_loc;
            float4 v;
            if (f < 8) v = qkv4[t * 12 + 4 + f];
            else       v = mkv4[t * 8 + (f - 8)];
            ((float4*)smem)[j] = v;
        }
        __syncthreads();

        const int t0 = part * 18;
        for (int tl = t0; tl < t0 + 18; ++tl) {
            const float* kvb = &smem[tl * 64];
            float kk[16], vv[16];
            LOAD16(kk, kvb);
            LOAD16(vv, kvb + 16);
            float d = 0.f;
#pragma unroll
            for (int j = 0; j < 16; ++j) d += q[j] * kk[j];
            d *= 0.25f;
            float mn = fmaxf(mh, d);
            float eo = __expf(mh - mn);
            float ex = __expf(d - mn);
            lh = lh * eo + ex;
#pragma unroll
            for (int j = 0; j < 16; ++j) oh[j] = oh[j] * eo + ex * vv[j];
            mh = mn;

            LOAD16(kk, kvb + 32);
            LOAD16(vv, kvb + 48);
            float d2 = 0.f;
#pragma unroll
            for (int j = 0; j < 16; ++j) d2 += q[j] * kk[j];
            d2 *= 0.25f;
            float mn2 = fmaxf(mm, d2);
            float eo2 = __expf(mm - mn2);
            float ex2 = __expf(d2 - mn2);
            lm = lm * eo2 + ex2;
#pragma unroll
            for (int j = 0; j < 16; ++j) om[j] = om[j] * eo2 + ex2 * vv[j];
            mm = mn2;
        }
    }

    __syncthreads();   // done reading kv area; reuse as reduction scratch
    float* rp = &smem[(row * 8 + part) * 38];
    rp[0] = mh; rp[1] = lh;
#pragma unroll
    for (int j = 0; j < 16; ++j) rp[2 + j] = oh[j];
    rp[18] = mm; rp[19] = lm;
#pragma unroll
    for (int j = 0; j < 16; ++j) rp[20 + j] = om[j];
    __syncthreads();

    for (int off = 4; off >= 1; off >>= 1) {
        if (part < off) {
            float* a = &smem[(row * 8 + part) * 38];
            float* bq = &smem[(row * 8 + part + off) * 38];
            {
                float ma = a[0], mb_ = bq[0];
                float mn = fmaxf(ma, mb_);
                float ea = __expf(ma - mn), eb = __expf(mb_ - mn);
                a[0] = mn; a[1] = a[1] * ea + bq[1] * eb;
#pragma unroll
                for (int j = 0; j < 16; ++j) a[2 + j] = a[2 + j] * ea + bq[2 + j] * eb;
            }
            {
                float ma = a[18], mb_ = bq[18];
                float mn = fmaxf(ma, mb_);
                float ea = __expf(ma - mn), eb = __expf(mb_ - mn);
                a[18] = mn; a[19] = a[19] * ea + bq[19] * eb;
#pragma unroll
                for (int j = 0; j < 16; ++j) a[20 + j] = a[20 + j] * ea + bq[20 + j] * eb;
            }
        }
        __syncthreads();
    }

    // fused z = z_w @ [Zh;Zm] + z_b ; each partial-thread does 2 channels
    const float* rp0 = &smem[(row * 8) * 38];
    float ilh = 1.f / rp0[1];
    float ilm = 1.f / rp0[19];
    int y = s / WW, x = s % WW;
#pragma unroll
    for (int zc2 = 0; zc2 < 2; ++zc2) {
        int zc = part * 2 + zc2;
        const float* zr = &zw[zc * 32];
        float accz = zb[zc];
#pragma unroll
        for (int j = 0; j < 16; ++j) accz += zr[j] * (rp0[2 + j] * ilh);
#pragma unroll
        for (int j = 0; j < 16; ++j) accz += zr[16 + j] * (rp0[20 + j] * ilm);
        Z[((size_t)(n * DATT + zc) * PR + y + 1) * PC + x + 1] = accz;
    }
}

// ---------------- SA memory gates (h written padded) ----------------
__global__ void k_sa_gates(const float* __restrict__ iog, float* __restrict__ m,
                           float* __restrict__ h) {
    int i = blockIdx.x * blockDim.x + threadIdx.x;
    if (i >= NB * HD * SS) return;
    int s = i % SS;
    int ch = (i / SS) % HD;
    int n = i / (HD * SS);
    const float* ib = iog + (size_t)n * 3 * HD * SS;
    float si = ib[ch * SS + s];
    float sg = ib[(HD + ch) * SS + s];
    float so = ib[(2 * HD + ch) * SS + s];
    si = sigmoidf_(si);
    sg = tanhf(sg);
    float mn = si * sg + (1.f - si) * m[i];
    m[i] = mn;
    int y = s / WW, x = s % WW;
    h[((size_t)(n * HD + ch) * PR + (y + 1)) * PC + (x + 1)] = sigmoidf_(so) * mn;
}

// ---------------- out 1x1 conv (64 -> 2), padded h -> d_out[t] ----------------
__global__ void k_out(const float* __restrict__ h, const float* __restrict__ ow,
                      const float* __restrict__ ob, float* __restrict__ outbuf, int t) {
    int idx = blockIdx.x * blockDim.x + threadIdx.x;
    if (idx >= NB * SS) return;
    int s = idx % SS;
    int n = idx / SS;
    int y = s / WW, x = s % WW;
    float reg[HD];
    const float* src = h + (size_t)n * HD * PHW + (y + 1) * PC + (x + 1);
#pragma unroll
    for (int ic = 0; ic < HD; ++ic) reg[ic] = src[ic * PHW];
#pragma unroll
    for (int cc = 0; cc < NCOUT; ++cc) {
        const float* wr = &ow[cc * HD];
        float a = ob[cc];
#pragma unroll
        for (int ic = 0; ic < HD; ++ic) a += reg[ic] * wr[ic];
        outbuf[(((size_t)n * TSTEPS + t) * NCOUT + cc) * SS + s] = a;
    }
}

// ---------------- nino prediction ----------------
__global__ void k_nino(const float* __restrict__ outbuf, float* __restrict__ pred) {
    int tidx = threadIdx.x;
    if (tidx >= 16 * 24) return;
    int j = tidx % 24;
    int n = tidx / 24;
    float acc = 0.f;
    for (int f = j; f < j + 3; ++f) {
        int t = 11 + f;
        const float* p = &outbuf[(((size_t)n * TSTEPS + t) * NCOUT + 0) * SS];
        float sloc = 0.f;
        for (int y = 10; y <= 12; ++y)
            for (int x = 19; x <= 29; ++x)
                sloc += p[y * WW + x];
        acc += sloc * (1.f / 33.f);
    }
    pred[n * 24 + j] = acc * (1.f / 3.f);
}

extern "C" void kernel_launch(void* const* d_in, const int* in_sizes, int n_in,
                              void* d_out, int out_size, void* d_ws, size_t ws_size,
                              hipStream_t stream) {
    const float* x      = (const float*)d_in[0];
    const float* conv_w = (const float*)d_in[1];
    const float* conv_b = (const float*)d_in[2];
    const float* h_w    = (const float*)d_in[3];
    const float* h_b    = (const float*)d_in[4];
    const float* m_w    = (const float*)d_in[5];
    const float* m_b    = (const float*)d_in[6];
    const float* z_w    = (const float*)d_in[7];
    const float* z_b    = (const float*)d_in[8];
    const float* o_w    = (const float*)d_in[9];
    const float* o_b    = (const float*)d_in[10];
    const float* out_w  = (const float*)d_in[11];
    const float* out_b  = (const float*)d_in[12];

    float* ws   = (float*)d_ws;
    float* h    = ws + OFF_H;
    float* c    = ws + OFF_C;
    float* m    = ws + OFF_M;
    float* feed = ws + OFF_FEED;
    float* comb = ws + OFF_COMB;
    float* qkv  = ws + OFF_QKV;
    float* mkv  = ws + OFF_MKV;
    float* Zb   = ws + OFF_Z;
    float* iog  = ws + OFF_IOG;
    float* w2g  = ws + OFF_W2G;
    float* w3g  = ws + OFF_W3G;
    float* outp = (float*)d_out;

    // zero h (padded), c, m, feed (padded), Z (padded): 4154752 floats = 1038688 f4
    k_zero<<<4058, 256, 0, stream>>>(ws, 1038688);
    k_prep_w2g<<<648, 256, 0, stream>>>(conv_w, w2g);
    k_prep_w3g<<<540, 256, 0, stream>>>(o_w, w3g);

    for (int t = 0; t < TSTEPS; ++t) {
        k_feed<<<216, 256, 0, stream>>>(x, outp, feed, t);
        k_conv3x3<<<dim3(48, 32), 192, 0, stream>>>(feed, 3, h, HD, w2g, conv_b,
                                                    comb, 4 * HD);
        k_lstm_gates<<<4608, 256, 0, stream>>>(comb, c, h);
        k_qkv<<<dim3(72, 10), 256, 0, stream>>>(h, m, h_w, h_b, m_w, m_b, qkv, mkv);
        k_attn<<<dim3(36, 16), 256, 0, stream>>>(qkv, mkv, z_w, z_b, Zb);
        k_conv3x3<<<dim3(48, 24), 192, 0, stream>>>(Zb, DATT, h, HD, w3g, o_b,
                                                    iog, 3 * HD);
        k_sa_gates<<<4608, 256, 0, stream>>>(iog, m, h);
        k_out<<<72, 256, 0, stream>>>(h, out_w, out_b, outp, t);
    }
    k_nino<<<1, 384, 0, stream>>>(outp, outp + (size_t)NB * TSTEPS * NCOUT * SS);
}